// Round 2
// baseline (1567.986 us; speedup 1.0000x reference)
//
#include <hip/hip_runtime.h>
#include <math.h>

// ---------------- kernels ----------------

__global__ void deg_kernel(const int* __restrict__ dst, int* __restrict__ cnt, int E) {
    int tid = blockIdx.x * blockDim.x + threadIdx.x;
    int stride = gridDim.x * blockDim.x;
    for (int e = tid; e < E; e += stride)
        atomicAdd(&cnt[dst[e]], 1);
}

__global__ void dinv_kernel(const int* __restrict__ cnt, float* __restrict__ dinv, int N) {
    int tid = blockIdx.x * blockDim.x + threadIdx.x;
    int stride = gridDim.x * blockDim.x;
    for (int v = tid; v < N; v += stride)
        dinv[v] = rsqrtf((float)(cnt[v] + 1));   // +1 self loop; always > 0
}

// out[N,C] = X[N,K] @ W[K,C]; one wave per row, lane = col. W staged in LDS.
template <int K, int C>
__global__ void gemm_kernel(const float* __restrict__ X, const float* __restrict__ W,
                            float* __restrict__ out, int N) {
    __shared__ float Ws[K * C];
    for (int i = threadIdx.x; i < K * C; i += blockDim.x) Ws[i] = W[i];
    __syncthreads();
    int gtid = blockIdx.x * blockDim.x + threadIdx.x;
    int wave = gtid >> 6;
    int lane = threadIdx.x & 63;
    int nw = (gridDim.x * blockDim.x) >> 6;
    for (int row = wave; row < N; row += nw) {
        if (lane < C) {
            const float4* xr = (const float4*)(X + (size_t)row * K);
            float acc = 0.f;
#pragma unroll
            for (int k4 = 0; k4 < K / 4; ++k4) {
                float4 v = xr[k4];
                int k = k4 * 4;
                acc += v.x * Ws[(k + 0) * C + lane] + v.y * Ws[(k + 1) * C + lane]
                     + v.z * Ws[(k + 2) * C + lane] + v.w * Ws[(k + 3) * C + lane];
            }
            out[(size_t)row * C + lane] = acc;
        }
    }
}

// out[dst,:] += feat[src,:] * dinv[src]*dinv[dst]; one wave per edge, lane = col.
template <int C>
__global__ void scatter_kernel(const float* __restrict__ feat, const int* __restrict__ src,
                               const int* __restrict__ dst, const float* __restrict__ dinv,
                               float* __restrict__ out, int E) {
    int gtid = blockIdx.x * blockDim.x + threadIdx.x;
    int wave = gtid >> 6;
    int lane = threadIdx.x & 63;
    int nw = (gridDim.x * blockDim.x) >> 6;
    for (int e = wave; e < E; e += nw) {
        int s = src[e];
        int d = dst[e];
        float norm = dinv[s] * dinv[d];
        if (lane < C)
            atomicAdd(&out[(size_t)d * C + lane], feat[(size_t)s * C + lane] * norm);
    }
}

// B = relu(B + A*dinv^2 (self loop) + bias), C=64
__global__ void bias_relu_kernel(float* __restrict__ B, const float* __restrict__ A,
                                 const float* __restrict__ dinv, const float* __restrict__ b, int N) {
    int tid = blockIdx.x * blockDim.x + threadIdx.x;
    int stride = gridDim.x * blockDim.x;
    int total = N * 64;
    for (int i = tid; i < total; i += stride) {
        int v = i >> 6;
        int j = i & 63;
        float di = dinv[v];
        float val = B[i] + A[i] * di * di + b[j];
        B[i] = val > 0.f ? val : 0.f;
    }
}

// out[v,:] = log_softmax(softmax(out[v,:] + A2[v,:]*dinv^2 + b)), row width 40, wave per row
__global__ void softmax_kernel(float* __restrict__ out, const float* __restrict__ A2,
                               const float* __restrict__ dinv, const float* __restrict__ b, int N) {
    int gtid = blockIdx.x * blockDim.x + threadIdx.x;
    int wave = gtid >> 6;
    int lane = threadIdx.x & 63;
    int nw = (gridDim.x * blockDim.x) >> 6;
    for (int v = wave; v < N; v += nw) {
        bool act = lane < 40;
        float di = dinv[v];
        size_t idx = (size_t)v * 40 + lane;
        float z = act ? (out[idx] + A2[idx] * di * di + b[lane]) : -INFINITY;
        // softmax
        float m = z;
        for (int off = 32; off; off >>= 1) m = fmaxf(m, __shfl_xor(m, off));
        float e = act ? expf(z - m) : 0.f;
        float s = e;
        for (int off = 32; off; off >>= 1) s += __shfl_xor(s, off);
        float p = e / s;
        // log_softmax of p
        float m2 = act ? p : -INFINITY;
        for (int off = 32; off; off >>= 1) m2 = fmaxf(m2, __shfl_xor(m2, off));
        float e2 = act ? expf(p - m2) : 0.f;
        float s2 = e2;
        for (int off = 32; off; off >>= 1) s2 += __shfl_xor(s2, off);
        if (act) out[idx] = (p - m2) - logf(s2);
    }
}

// ---------------- launch ----------------

extern "C" void kernel_launch(void* const* d_in, const int* in_sizes, int n_in,
                              void* d_out, int out_size, void* d_ws, size_t ws_size,
                              hipStream_t stream) {
    const float* x  = (const float*)d_in[0];
    const int*   ei = (const int*)d_in[1];     // harness converts integer inputs to int32
    const float* W1 = (const float*)d_in[2];
    const float* b1 = (const float*)d_in[3];
    const float* W2 = (const float*)d_in[4];
    const float* b2 = (const float*)d_in[5];
    float* out = (float*)d_out;

    int N = in_sizes[0] / 128;
    int E = in_sizes[1] / 2;
    const int* src = ei;
    const int* dst = ei + E;

    char* ws = (char*)d_ws;
    size_t o = 0;
    int*   cnt  = (int*)(ws + o);   o += (((size_t)N * 4) + 255) & ~(size_t)255;
    float* dinv = (float*)(ws + o); o += (((size_t)N * 4) + 255) & ~(size_t)255;
    float* A    = (float*)(ws + o); o += (((size_t)N * 64 * 4) + 255) & ~(size_t)255;
    float* B    = (float*)(ws + o); o += (((size_t)N * 64 * 4) + 255) & ~(size_t)255;

    // degree + norm
    hipMemsetAsync(cnt, 0, (size_t)N * 4, stream);
    deg_kernel<<<1024, 256, 0, stream>>>(dst, cnt, E);
    dinv_kernel<<<256, 256, 0, stream>>>(cnt, dinv, N);

    // layer 1: A = x@W1 ; B = scatter(A) ; B = relu(B + selfloop + b1)
    gemm_kernel<128, 64><<<2048, 256, 0, stream>>>(x, W1, A, N);
    hipMemsetAsync(B, 0, (size_t)N * 64 * 4, stream);
    scatter_kernel<64><<<4096, 256, 0, stream>>>(A, src, dst, dinv, B, E);
    bias_relu_kernel<<<2048, 256, 0, stream>>>(B, A, dinv, b1, N);

    // layer 2: A = B@W2 ; out = scatter(A) ; out = log_softmax(softmax(out + selfloop + b2))
    gemm_kernel<64, 40><<<2048, 256, 0, stream>>>(B, W2, A, N);
    hipMemsetAsync(out, 0, (size_t)N * 40 * 4, stream);
    scatter_kernel<40><<<4096, 256, 0, stream>>>(A, src, dst, dinv, out, E);
    softmax_kernel<<<2048, 256, 0, stream>>>(out, A, dinv, b2, N);
}